// Round 7
// baseline (704.049 us; speedup 1.0000x reference)
//
#include <hip/hip_runtime.h>
#include <hip/hip_bf16.h>

// ---------------------------------------------------------------------------
// STGCN fused pipeline, round 7.
// conv23 v6: same 4x-independent-wave structure as v5, but inner conv loops use
// v_pk_fma_f32 (packed 2xfp32) over t-pairs: halves FMA issue count.
// Weight broadcast via VOP3P op_sel (no dup movs); summation order identical
// to v5 -> bit-identical output.
// ---------------------------------------------------------------------------

#define NN 50000
#define NE 500000
#define NG 16
#define CAP 64

__device__ __forceinline__ float sigf(float g) {
    return 1.0f / (1.0f + __expf(-g));
}

// d = a * broadcast(w.lo) + c   (per 32-bit half)
__device__ __forceinline__ float2 pk_fma_lo(float2 a, float2 w, float2 c) {
    float2 d;
    asm("v_pk_fma_f32 %0, %1, %2, %3 op_sel_hi:[1,0,1]"
        : "=v"(d) : "v"(a), "v"(w), "v"(c));
    return d;
}
// d = a * broadcast(w.hi) + c
__device__ __forceinline__ float2 pk_fma_hi(float2 a, float2 w, float2 c) {
    float2 d;
    asm("v_pk_fma_f32 %0, %1, %2, %3 op_sel:[0,1,0] op_sel_hi:[1,1,1]"
        : "=v"(d) : "v"(a), "v"(w), "v"(c));
    return d;
}

// ---- bucket build ---------------------------------------------------------
__global__ void k_fill(const int* __restrict__ row, const int* __restrict__ col,
                       int* __restrict__ cnt, unsigned short* __restrict__ bucket,
                       int E)
{
    int e = blockIdx.x * 256 + threadIdx.x;
    if (e >= E) return;
    int c = col[e];
    int pos = atomicAdd(&cnt[c], 1);
    if (pos < CAP) bucket[(size_t)c * CAP + pos] = (unsigned short)row[e];
}

__global__ void k_dinv(const int* __restrict__ cnt, float* __restrict__ dinv, int n) {
    int i = blockIdx.x * 256 + threadIdx.x;
    if (i < n) dinv[i] = rsqrtf((float)cnt[i] + 1.0f);
}

// ---- weight repack --------------------------------------------------------
// p2: [c4(4)][i(4)][j(4)][l32(32)] float4 {k0,k1,k2,0}   (2048 float4)
// p3: [q(4)][c4(4)][i(4)][j(4)][l32(32)] float4 {k0,k1,k2,0} (8192 float4)
// pw: [q(4)][cl4(4)][l16(16)] float4 (proj, unchanged)    (256 float4)
// o(j,l32) = (j&1)*32 + l32 + (j>>1)*64
__global__ void k_prep(const float* __restrict__ w1b, const float* __restrict__ w2a,
                       const float* __restrict__ ws2,
                       float4* __restrict__ p2, float4* __restrict__ p3,
                       float4* __restrict__ pw)
{
    int i = blockIdx.x * 256 + threadIdx.x;
    if (i < 2048) {
        int l32 = i & 31; int r = i >> 5;
        int j = r & 3; int r2 = r >> 2;
        int ii = r2 & 3; int c4 = r2 >> 2;
        int o = (j & 1) * 32 + l32 + (j >> 1) * 64;
        int ci = c4 * 4 + ii;
        p2[i] = make_float4(w1b[o * 48 + ci * 3 + 0],
                            w1b[o * 48 + ci * 3 + 1],
                            w1b[o * 48 + ci * 3 + 2], 0.f);
    }
    if (i < 8192) {
        int l32 = i & 31; int r = i >> 5;
        int j = r & 3; int r2 = r >> 2;
        int ii = r2 & 3; int r3 = r2 >> 2;
        int c4 = r3 & 3; int q = r3 >> 2;
        int o = (j & 1) * 32 + l32 + (j >> 1) * 64;
        int ci = q * 16 + c4 * 4 + ii;
        p3[i] = make_float4(w2a[o * 192 + ci * 3 + 0],
                            w2a[o * 192 + ci * 3 + 1],
                            w2a[o * 192 + ci * 3 + 2], 0.f);
    }
    if (i < 256) {
        int l16 = i & 15; int r = i >> 4;
        int cl4 = r & 3; int q = r >> 2;
        float4 v;
        v.x = ws2[(q * 16 + cl4 * 4 + 0) * 16 + l16];
        v.y = ws2[(q * 16 + cl4 * 4 + 1) * 16 + l16];
        v.z = ws2[(q * 16 + cl4 * 4 + 2) * 16 + l16];
        v.w = ws2[(q * 16 + cl4 * 4 + 3) * 16 + l16];
        pw[i] = v;
    }
}

// ---- conv_glu1 + proj (unchanged) -----------------------------------------
__global__ __launch_bounds__(256) void k_conv1_proj(
    const float* __restrict__ x, const float* __restrict__ w,
    const float* __restrict__ b, const float* __restrict__ W1,
    const float* __restrict__ dinv, float* __restrict__ xw1, int nNodes)
{
    __shared__ float ws[768];
    __shared__ float bs[128];
    __shared__ float W1s[1024];
    int tid = threadIdx.x;
    for (int i = tid; i < 768;  i += 256) ws[i]  = w[i];
    for (int i = tid; i < 1024; i += 256) W1s[i] = W1[i];
    if (tid < 128) bs[tid] = b[tid];
    __syncthreads();

    int idx = blockIdx.x * 256 + tid;
    if (idx >= nNodes * 10) return;
    int n = idx / 10, t = idx % 10;

    float xr[6];
#pragma unroll
    for (int ci = 0; ci < 2; ++ci)
#pragma unroll
        for (int k = 0; k < 3; ++k)
            xr[ci * 3 + k] = x[n * 24 + ci * 12 + t + k];

    float acc[16];
#pragma unroll
    for (int d = 0; d < 16; ++d) acc[d] = 0.f;

    for (int c = 0; c < 64; ++c) {
        float a = bs[c], g = bs[c + 64];
#pragma unroll
        for (int j = 0; j < 6; ++j) {
            a = fmaf(ws[c * 6 + j],        xr[j], a);
            g = fmaf(ws[(c + 64) * 6 + j], xr[j], g);
        }
        float h = a * sigf(g);
#pragma unroll
        for (int d = 0; d < 16; ++d) acc[d] = fmaf(W1s[c * 16 + d], h, acc[d]);
    }
    float dv = dinv[n];
    float* o = &xw1[n * 160 + t * 16];
#pragma unroll
    for (int d = 0; d < 16; ++d) o[d] = acc[d] * dv;
}

// ---- GCN gather (float4, unchanged) ---------------------------------------
template <int W>
__global__ __launch_bounds__(256) void k_gather(
    const float* __restrict__ xs, const unsigned short* __restrict__ bucket,
    const int* __restrict__ cnt, const float* __restrict__ dinv,
    const float* __restrict__ bias, float* __restrict__ h, int nNodes)
{
    constexpr int W4 = W / 4;
    int wid  = (blockIdx.x * 256 + threadIdx.x) >> 6;
    int lane = threadIdx.x & 63;
    if (wid >= nNodes) return;
    const int c = wid;
    const int deg = min(cnt[c], CAP);

    int myid = 0;
    if (lane < deg) myid = (int)bucket[(size_t)c * CAP + lane];

    const float4* xs4 = (const float4*)xs;
    float4 acc = make_float4(0.f, 0.f, 0.f, 0.f);
    for (int j = 0; j < deg; ++j) {
        int r = __shfl(myid, j);
        if (lane < W4) {
            float4 v = xs4[(size_t)r * W4 + lane];
            acc.x += v.x; acc.y += v.y; acc.z += v.z; acc.w += v.w;
        }
    }

    if (lane < W4) {
        const float dv = dinv[c];
        float4 s  = xs4[(size_t)c * W4 + lane];
        float4 b4 = ((const float4*)bias)[lane & 3];
        float4 o;
        o.x = fmaxf(dv * (acc.x + s.x) + b4.x, 0.f);
        o.y = fmaxf(dv * (acc.y + s.y) + b4.y, 0.f);
        o.z = fmaxf(dv * (acc.z + s.z) + b4.z, 0.f);
        o.w = fmaxf(dv * (acc.w + s.w) + b4.w, 0.f);
        ((float4*)h)[(size_t)c * W4 + lane] = o;
    }
}

// ---------------------------------------------------------------------------
// conv23 v6: v5 structure, packed-fp32 inner loops.
// ---------------------------------------------------------------------------
__global__ __launch_bounds__(256) void k_conv23_v6(
    const float* __restrict__ h2g, const float4* __restrict__ p2,
    const float* __restrict__ b1b, const float4* __restrict__ p3,
    const float* __restrict__ b2a, const float4* __restrict__ pw,
    const float* __restrict__ dinv, float* __restrict__ xw2)
{
    __shared__ float h2s[4][392];  // per-wave [node2][ci16][t pad12] stride 196
    __shared__ float h3q[4][264];  // per-wave quarter buf [node2][132]

    const int tid  = threadIdx.x;
    const int wid  = tid >> 6;
    const int lane = tid & 63;
    const int l32  = lane & 31;
    const int nl   = lane >> 5;
    const int base = blockIdx.x * 8 + wid * 2;
    const int node = base + nl;

    float* h2w = h2s[wid];
    float* h3w = h3q[wid];

    // ---- stage h2 (2 nodes x 160), transposed to [ci][t] ----
#pragma unroll
    for (int it = 0; it < 2; ++it) {
        int i = lane + it * 64;
        if (i < 80) {
            int ns = i / 40, r4 = i - ns * 40;
            int t = r4 >> 2, ci0 = (r4 & 3) << 2;
            float4 v = *(const float4*)&h2g[(size_t)(base + ns) * 160 + t * 16 + ci0];
            float* hp = &h2w[ns * 196 + ci0 * 12 + t];
            hp[0]  = v.x;
            hp[12] = v.y;
            hp[24] = v.z;
            hp[36] = v.w;
        }
    }

    // ---- conv2: (16,10) -> (64+64, 8), packed over t-pairs ----
    float2 acc2[4][4];
    {
        float b0 = b1b[l32], b1 = b1b[l32 + 32], b2 = b1b[64 + l32], b3 = b1b[96 + l32];
#pragma unroll
        for (int p = 0; p < 4; ++p) {
            acc2[0][p] = make_float2(b0, b0);
            acc2[1][p] = make_float2(b1, b1);
            acc2[2][p] = make_float2(b2, b2);
            acc2[3][p] = make_float2(b3, b3);
        }
    }

#pragma unroll 1
    for (int c4 = 0; c4 < 4; ++c4) {
#pragma unroll
        for (int i = 0; i < 4; ++i) {
            const float* hp = &h2w[nl * 196 + (c4 * 4 + i) * 12];
            float4 v0 = *(const float4*)(hp);
            float4 v1 = *(const float4*)(hp + 4);
            float2 v2 = *(const float2*)(hp + 8);
            // even pairs (t, t+1) for k=0: (0,1)(2,3)(4,5)(6,7)
            float2 pe0 = make_float2(v0.x, v0.y);
            float2 pe1 = make_float2(v0.z, v0.w);
            float2 pe2 = make_float2(v1.x, v1.y);
            float2 pe3 = make_float2(v1.z, v1.w);
            // odd pairs for k=1: (1,2)(3,4)(5,6)(7,8)
            float2 po0 = make_float2(v0.y, v0.z);
            float2 po1 = make_float2(v0.w, v1.x);
            float2 po2 = make_float2(v1.y, v1.z);
            float2 po3 = make_float2(v1.w, v2.x);
            // k=2 tail pair (8,9)
            float2 p89 = make_float2(v2.x, v2.y);
#pragma unroll
            for (int j = 0; j < 4; ++j) {
                float4 wv = p2[(((c4 * 4 + i) << 2) + j) * 32 + l32];
                float2 w01 = make_float2(wv.x, wv.y);
                float2 w2p = make_float2(wv.z, wv.w);
                // k=0: w.k0 (lo of w01)
                acc2[j][0] = pk_fma_lo(pe0, w01, acc2[j][0]);
                acc2[j][1] = pk_fma_lo(pe1, w01, acc2[j][1]);
                acc2[j][2] = pk_fma_lo(pe2, w01, acc2[j][2]);
                acc2[j][3] = pk_fma_lo(pe3, w01, acc2[j][3]);
                // k=1: w.k1 (hi of w01)
                acc2[j][0] = pk_fma_hi(po0, w01, acc2[j][0]);
                acc2[j][1] = pk_fma_hi(po1, w01, acc2[j][1]);
                acc2[j][2] = pk_fma_hi(po2, w01, acc2[j][2]);
                acc2[j][3] = pk_fma_hi(po3, w01, acc2[j][3]);
                // k=2: w.k2 (lo of w2p); pairs (2,3)(4,5)(6,7)(8,9)
                acc2[j][0] = pk_fma_lo(pe1, w2p, acc2[j][0]);
                acc2[j][1] = pk_fma_lo(pe2, w2p, acc2[j][1]);
                acc2[j][2] = pk_fma_lo(pe3, w2p, acc2[j][2]);
                acc2[j][3] = pk_fma_lo(p89, w2p, acc2[j][3]);
            }
        }
    }

    // GLU -> h3 pairs: h3p[s] = a_s * sig(g_s), s=0: co=l32, s=1: co=l32+32
    float2 h3p[2][4];
#pragma unroll
    for (int p = 0; p < 4; ++p) {
        h3p[0][p] = make_float2(acc2[0][p].x * sigf(acc2[2][p].x),
                                acc2[0][p].y * sigf(acc2[2][p].y));
        h3p[1][p] = make_float2(acc2[1][p].x * sigf(acc2[3][p].x),
                                acc2[1][p].y * sigf(acc2[3][p].y));
    }

    // ---- conv3: (64,8) -> (64+64, 6), quarter-streamed, packed ----
    float2 c32[4][3];
    {
        float b0 = b2a[l32], b1 = b2a[l32 + 32], b2 = b2a[64 + l32], b3 = b2a[96 + l32];
#pragma unroll
        for (int p = 0; p < 3; ++p) {
            c32[0][p] = make_float2(b0, b0);
            c32[1][p] = make_float2(b1, b1);
            c32[2][p] = make_float2(b2, b2);
            c32[3][p] = make_float2(b3, b3);
        }
    }

#pragma unroll 1
    for (int q = 0; q < 4; ++q) {
        const int srcA = (q < 2);
        const int own  = srcA ? ((l32 >> 4) == q) : ((l32 >> 4) == (q - 2));
        float vq[8];
#pragma unroll
        for (int t = 0; t < 8; ++t) {
            float2 s = srcA ? h3p[0][t >> 1] : h3p[1][t >> 1];
            vq[t] = (t & 1) ? s.y : s.x;
        }
        if (own) {
            float* hp = &h3w[nl * 132 + (l32 & 15) * 8];
            *(float4*)(hp)     = make_float4(vq[0], vq[1], vq[2], vq[3]);
            *(float4*)(hp + 4) = make_float4(vq[4], vq[5], vq[6], vq[7]);
        }
#pragma unroll 1
        for (int c4 = 0; c4 < 4; ++c4) {
#pragma unroll
            for (int i = 0; i < 4; ++i) {
                const float* hp = &h3w[nl * 132 + (c4 * 4 + i) * 8];
                float4 v0 = *(const float4*)(hp);
                float4 v1 = *(const float4*)(hp + 4);
                float2 pe0 = make_float2(v0.x, v0.y);   // (0,1)
                float2 pe1 = make_float2(v0.z, v0.w);   // (2,3)
                float2 pe2 = make_float2(v1.x, v1.y);   // (4,5)
                float2 po0 = make_float2(v0.y, v0.z);   // (1,2)
                float2 po1 = make_float2(v0.w, v1.x);   // (3,4)
                float2 po2 = make_float2(v1.y, v1.z);   // (5,6)
                float2 p67 = make_float2(v1.z, v1.w);   // (6,7)
#pragma unroll
                for (int j = 0; j < 4; ++j) {
                    float4 wv = p3[((((q * 4 + c4) * 4 + i) << 2) + j) * 32 + l32];
                    float2 w01 = make_float2(wv.x, wv.y);
                    float2 w2p = make_float2(wv.z, wv.w);
                    c32[j][0] = pk_fma_lo(pe0, w01, c32[j][0]);
                    c32[j][1] = pk_fma_lo(pe1, w01, c32[j][1]);
                    c32[j][2] = pk_fma_lo(pe2, w01, c32[j][2]);
                    c32[j][0] = pk_fma_hi(po0, w01, c32[j][0]);
                    c32[j][1] = pk_fma_hi(po1, w01, c32[j][1]);
                    c32[j][2] = pk_fma_hi(po2, w01, c32[j][2]);
                    c32[j][0] = pk_fma_lo(pe1, w2p, c32[j][0]);
                    c32[j][1] = pk_fma_lo(pe2, w2p, c32[j][1]);
                    c32[j][2] = pk_fma_lo(p67, w2p, c32[j][2]);
                }
            }
        }
    }

    // ---- GLU + proj 64->16 (scalar, as v5) ----
    float h4r[2][6];
#pragma unroll
    for (int t = 0; t < 6; ++t) {
        float a0 = (t & 1) ? c32[0][t >> 1].y : c32[0][t >> 1].x;
        float g0 = (t & 1) ? c32[2][t >> 1].y : c32[2][t >> 1].x;
        float a1 = (t & 1) ? c32[1][t >> 1].y : c32[1][t >> 1].x;
        float g1 = (t & 1) ? c32[3][t >> 1].y : c32[3][t >> 1].x;
        h4r[0][t] = a0 * sigf(g0);
        h4r[1][t] = a1 * sigf(g1);
    }

    float pacc[3] = {0.f, 0.f, 0.f};
    const int d  = l32 & 15;
    const int th = l32 >> 4;

#pragma unroll 1
    for (int q = 0; q < 4; ++q) {
        const int srcA = (q < 2);
        const int own  = srcA ? ((l32 >> 4) == q) : ((l32 >> 4) == (q - 2));
        float v[6];
#pragma unroll
        for (int t = 0; t < 6; ++t) v[t] = srcA ? h4r[0][t] : h4r[1][t];
        if (own) {
            float* hp = &h3w[nl * 132 + (l32 & 15) * 8];
            *(float4*)(hp)     = make_float4(v[0], v[1], v[2], v[3]);
            *(float2*)(hp + 4) = make_float2(v[4], v[5]);
        }
        float4 wv0 = pw[(q * 4 + 0) * 16 + d];
        float4 wv1 = pw[(q * 4 + 1) * 16 + d];
        float4 wv2 = pw[(q * 4 + 2) * 16 + d];
        float4 wv3 = pw[(q * 4 + 3) * 16 + d];
        float wq[16];
        wq[0]  = wv0.x; wq[1]  = wv0.y; wq[2]  = wv0.z; wq[3]  = wv0.w;
        wq[4]  = wv1.x; wq[5]  = wv1.y; wq[6]  = wv1.z; wq[7]  = wv1.w;
        wq[8]  = wv2.x; wq[9]  = wv2.y; wq[10] = wv2.z; wq[11] = wv2.w;
        wq[12] = wv3.x; wq[13] = wv3.y; wq[14] = wv3.z; wq[15] = wv3.w;
#pragma unroll
        for (int cl = 0; cl < 16; ++cl) {
            const float* hp = &h3w[nl * 132 + cl * 8];
            float4 e0 = *(const float4*)(hp);
            float2 e1 = *(const float2*)(hp + 4);
            float s0 = th ? e0.w : e0.x;
            float s1 = th ? e1.x : e0.y;
            float s2 = th ? e1.y : e0.z;
            pacc[0] = fmaf(wq[cl], s0, pacc[0]);
            pacc[1] = fmaf(wq[cl], s1, pacc[1]);
            pacc[2] = fmaf(wq[cl], s2, pacc[2]);
        }
    }

    const float dv = dinv[node];
#pragma unroll
    for (int s = 0; s < 3; ++s)
        xw2[(size_t)node * 96 + (th * 3 + s) * 16 + d] = pacc[s] * dv;
}

// ---- counts per graph -----------------------------------------------------
__global__ void k_counts(const int* __restrict__ batch, float* __restrict__ cnt,
                         int n, int ngraphs)
{
    int g = threadIdx.x;
    if (g >= ngraphs) return;
    int lo = 0, hi = n;
    while (lo < hi) { int m = (lo + hi) >> 1; if (batch[m] < g) lo = m + 1; else hi = m; }
    int lo2 = 0, hi2 = n;
    while (lo2 < hi2) { int m = (lo2 + hi2) >> 1; if (batch[m] < g + 1) lo2 = m + 1; else hi2 = m; }
    cnt[g] = (float)(lo2 - lo);
}

// ---- mean-pool numerator --------------------------------------------------
__global__ __launch_bounds__(128) void k_pool(
    const float* __restrict__ h5, const int* __restrict__ batch,
    float* __restrict__ pool, int nNodes)
{
    int j = threadIdx.x;
    if (j >= 96) return;
    int n0 = blockIdx.x * 64;
    int n1 = min(n0 + 64, nNodes);
    int cur = batch[n0];
    float acc = 0.f;
    for (int n = n0; n < n1; ++n) {
        int g = batch[n];
        if (g != cur) { atomicAdd(&pool[cur * 96 + j], acc); acc = 0.f; cur = g; }
        acc += h5[(size_t)n * 96 + j];
    }
    atomicAdd(&pool[cur * 96 + j], acc);
}

// ---- final conv_glu -------------------------------------------------------
__global__ __launch_bounds__(256) void k_final(
    const float* __restrict__ pool, const float* __restrict__ cnt,
    const float* __restrict__ w, const float* __restrict__ b,
    float* __restrict__ out)
{
    __shared__ float m[96];
    __shared__ float ws[6144];
    __shared__ float bs[128];
    int g = blockIdx.x, tid = threadIdx.x;
    if (tid < 96) m[tid] = pool[g * 96 + tid] / fmaxf(cnt[g], 1.0f);
    for (int i = tid; i < 6144; i += 256) ws[i] = w[i];
    if (tid < 128) bs[tid] = b[tid];
    __syncthreads();

    int c = tid >> 2, t = tid & 3;
    float a = bs[c], gg = bs[c + 64];
#pragma unroll
    for (int ci = 0; ci < 16; ++ci)
#pragma unroll
        for (int k = 0; k < 3; ++k) {
            float xv = m[(t + k) * 16 + ci];
            a  = fmaf(ws[c * 48 + ci * 3 + k],        xv, a);
            gg = fmaf(ws[(c + 64) * 48 + ci * 3 + k], xv, gg);
        }
    out[g * 256 + c * 4 + t] = a * sigf(gg);
}

// ---------------------------------------------------------------------------
extern "C" void kernel_launch(void* const* d_in, const int* in_sizes, int n_in,
                              void* d_out, int out_size, void* d_ws, size_t ws_size,
                              hipStream_t stream)
{
    const float* x      = (const float*)d_in[0];
    const int*   ei     = (const int*)  d_in[1];
    const int*   batch  = (const int*)  d_in[2];
    const float* w_t1a  = (const float*)d_in[3];
    const float* b_t1a  = (const float*)d_in[4];
    const float* w_s1   = (const float*)d_in[5];
    const float* bb_s1  = (const float*)d_in[6];
    const float* w_t1b  = (const float*)d_in[7];
    const float* b_t1b  = (const float*)d_in[8];
    const float* w_t2a  = (const float*)d_in[9];
    const float* b_t2a  = (const float*)d_in[10];
    const float* w_s2   = (const float*)d_in[11];
    const float* bb_s2  = (const float*)d_in[12];
    const float* w_t2b  = (const float*)d_in[13];
    const float* b_t2b  = (const float*)d_in[14];
    float* out = (float*)d_out;

    const int* row = ei;
    const int* col = ei + NE;

    // workspace layout
    float* F    = (float*)d_ws;
    float* xw   = F;                         // NN*160
    float* h    = xw + (size_t)NN * 160;     // NN*160
    float* p2f  = h  + (size_t)NN * 160;     // 8192
    float* p3f  = p2f + 8192;                // 32768
    float* pwf  = p3f + 32768;               // 1024
    float* dinv = pwf + 1024;                // NN
    float* pool = dinv + NN;                 // NG*96
    float* gcnt = pool + NG * 96;            // NG
    int*   cnt  = (int*)(gcnt + NG);         // NN ints
    unsigned short* bucket = (unsigned short*)(cnt + NN); // NN*CAP ushort

    hipMemsetAsync(cnt,  0, (size_t)NN * sizeof(int), stream);
    hipMemsetAsync(pool, 0, (size_t)NG * 96 * sizeof(float), stream);

    k_fill<<<(NE + 255) / 256, 256, 0, stream>>>(row, col, cnt, bucket, NE);
    k_dinv<<<(NN + 255) / 256, 256, 0, stream>>>(cnt, dinv, NN);
    k_prep<<<32, 256, 0, stream>>>(w_t1b, w_t2a, w_s2,
                                   (float4*)p2f, (float4*)p3f, (float4*)pwf);

    k_conv1_proj<<<(NN * 10 + 255) / 256, 256, 0, stream>>>(
        x, w_t1a, b_t1a, w_s1, dinv, xw, NN);

    k_gather<160><<<(NN * 64) / 256, 256, 0, stream>>>(
        xw, bucket, cnt, dinv, bb_s1, h, NN);

    k_conv23_v6<<<NN / 8, 256, 0, stream>>>(
        h, (const float4*)p2f, b_t1b, (const float4*)p3f, b_t2a,
        (const float4*)pwf, dinv, xw);

    k_gather<96><<<(NN * 64) / 256, 256, 0, stream>>>(
        xw, bucket, cnt, dinv, bb_s2, h, NN);

    k_counts<<<1, 64, 0, stream>>>(batch, gcnt, NN, NG);
    k_pool<<<(NN + 63) / 64, 128, 0, stream>>>(h, batch, pool, NN);

    k_final<<<NG, 256, 0, stream>>>(pool, gcnt, w_t2b, b_t2b, out);
}

// Round 8
// 500.248 us; speedup vs baseline: 1.4074x; 1.4074x over previous
//
#include <hip/hip_runtime.h>
#include <hip/hip_bf16.h>

// ---------------------------------------------------------------------------
// STGCN fused pipeline, round 8.
// conv23 v7 = v5 (proven 313us) minus quarter-streaming: full per-wave h3
// LDS buffer [2 nodes][64 co][8 t] -> conv3 and proj become single flat loops,
// no cndmask q-selection, no per-quarter write/read fences. Same summation
// order as v5 (bit-identical output). Everything else = round-6 file.
// ---------------------------------------------------------------------------

#define NN 50000
#define NE 500000
#define NG 16
#define CAP 64

__device__ __forceinline__ float sigf(float g) {
    return 1.0f / (1.0f + __expf(-g));
}

// ---- bucket build ---------------------------------------------------------
__global__ void k_fill(const int* __restrict__ row, const int* __restrict__ col,
                       int* __restrict__ cnt, unsigned short* __restrict__ bucket,
                       int E)
{
    int e = blockIdx.x * 256 + threadIdx.x;
    if (e >= E) return;
    int c = col[e];
    int pos = atomicAdd(&cnt[c], 1);
    if (pos < CAP) bucket[(size_t)c * CAP + pos] = (unsigned short)row[e];
}

__global__ void k_dinv(const int* __restrict__ cnt, float* __restrict__ dinv, int n) {
    int i = blockIdx.x * 256 + threadIdx.x;
    if (i < n) dinv[i] = rsqrtf((float)cnt[i] + 1.0f);
}

// ---- weight repack (v5 layout) --------------------------------------------
// p2: [c4(4)][o(128)-as-(j,l32)][kv(3)] float4 groups; index ((c4*4+j)*3+kv)*32+l32
// p3: same with leading ci16 = 0..15; index ((c16*4+j)*3+kv)*32+l32
// pw: [cl4(16)][l16(16)] float4 (components = 4 channels cl4*4+c at output d=l16)
// o(j,l32) = (j&1)*32 + l32 + (j>>1)*64
__global__ void k_prep(const float* __restrict__ w1b, const float* __restrict__ w2a,
                       const float* __restrict__ ws2,
                       float4* __restrict__ p2, float4* __restrict__ p3,
                       float4* __restrict__ pw)
{
    int i = blockIdx.x * 256 + threadIdx.x;
    if (i < 1536) {
        int l32 = i & 31; int r = i >> 5;
        int kv = r % 3; r /= 3;
        int j = r & 3; int c4 = r >> 2;
        int o = (j & 1) * 32 + l32 + (j >> 1) * 64;
        p2[i] = *(const float4*)&w1b[o * 48 + c4 * 12 + kv * 4];
    }
    if (i < 6144) {
        int l32 = i & 31; int r = i >> 5;
        int kv = r % 3; r /= 3;
        int j = r & 3; int c16 = r >> 2;
        int o = (j & 1) * 32 + l32 + (j >> 1) * 64;
        p3[i] = *(const float4*)&w2a[o * 192 + c16 * 12 + kv * 4];
    }
    if (i < 256) {
        int l16 = i & 15; int cl4 = i >> 4;
        float4 v;
        v.x = ws2[(cl4 * 4 + 0) * 16 + l16];
        v.y = ws2[(cl4 * 4 + 1) * 16 + l16];
        v.z = ws2[(cl4 * 4 + 2) * 16 + l16];
        v.w = ws2[(cl4 * 4 + 3) * 16 + l16];
        pw[i] = v;
    }
}

// ---- conv_glu1 + proj (unchanged) -----------------------------------------
__global__ __launch_bounds__(256) void k_conv1_proj(
    const float* __restrict__ x, const float* __restrict__ w,
    const float* __restrict__ b, const float* __restrict__ W1,
    const float* __restrict__ dinv, float* __restrict__ xw1, int nNodes)
{
    __shared__ float ws[768];
    __shared__ float bs[128];
    __shared__ float W1s[1024];
    int tid = threadIdx.x;
    for (int i = tid; i < 768;  i += 256) ws[i]  = w[i];
    for (int i = tid; i < 1024; i += 256) W1s[i] = W1[i];
    if (tid < 128) bs[tid] = b[tid];
    __syncthreads();

    int idx = blockIdx.x * 256 + tid;
    if (idx >= nNodes * 10) return;
    int n = idx / 10, t = idx % 10;

    float xr[6];
#pragma unroll
    for (int ci = 0; ci < 2; ++ci)
#pragma unroll
        for (int k = 0; k < 3; ++k)
            xr[ci * 3 + k] = x[n * 24 + ci * 12 + t + k];

    float acc[16];
#pragma unroll
    for (int d = 0; d < 16; ++d) acc[d] = 0.f;

    for (int c = 0; c < 64; ++c) {
        float a = bs[c], g = bs[c + 64];
#pragma unroll
        for (int j = 0; j < 6; ++j) {
            a = fmaf(ws[c * 6 + j],        xr[j], a);
            g = fmaf(ws[(c + 64) * 6 + j], xr[j], g);
        }
        float h = a * sigf(g);
#pragma unroll
        for (int d = 0; d < 16; ++d) acc[d] = fmaf(W1s[c * 16 + d], h, acc[d]);
    }
    float dv = dinv[n];
    float* o = &xw1[n * 160 + t * 16];
#pragma unroll
    for (int d = 0; d < 16; ++d) o[d] = acc[d] * dv;
}

// ---- GCN gather (float4, unchanged) ---------------------------------------
template <int W>
__global__ __launch_bounds__(256) void k_gather(
    const float* __restrict__ xs, const unsigned short* __restrict__ bucket,
    const int* __restrict__ cnt, const float* __restrict__ dinv,
    const float* __restrict__ bias, float* __restrict__ h, int nNodes)
{
    constexpr int W4 = W / 4;
    int wid  = (blockIdx.x * 256 + threadIdx.x) >> 6;
    int lane = threadIdx.x & 63;
    if (wid >= nNodes) return;
    const int c = wid;
    const int deg = min(cnt[c], CAP);

    int myid = 0;
    if (lane < deg) myid = (int)bucket[(size_t)c * CAP + lane];

    const float4* xs4 = (const float4*)xs;
    float4 acc = make_float4(0.f, 0.f, 0.f, 0.f);
    for (int j = 0; j < deg; ++j) {
        int r = __shfl(myid, j);
        if (lane < W4) {
            float4 v = xs4[(size_t)r * W4 + lane];
            acc.x += v.x; acc.y += v.y; acc.z += v.z; acc.w += v.w;
        }
    }

    if (lane < W4) {
        const float dv = dinv[c];
        float4 s  = xs4[(size_t)c * W4 + lane];
        float4 b4 = ((const float4*)bias)[lane & 3];
        float4 o;
        o.x = fmaxf(dv * (acc.x + s.x) + b4.x, 0.f);
        o.y = fmaxf(dv * (acc.y + s.y) + b4.y, 0.f);
        o.z = fmaxf(dv * (acc.z + s.z) + b4.z, 0.f);
        o.w = fmaxf(dv * (acc.w + s.w) + b4.w, 0.f);
        ((float4*)h)[(size_t)c * W4 + lane] = o;
    }
}

// ---------------------------------------------------------------------------
// conv23 v7: 4 independent waves/block, 2 nodes/wave, no barriers.
// Full h3 LDS buffer -> single-pass conv3 and proj (no quarter streaming).
// ---------------------------------------------------------------------------
__global__ __launch_bounds__(256) void k_conv23_v7(
    const float* __restrict__ h2g, const float4* __restrict__ p2,
    const float* __restrict__ b1b, const float4* __restrict__ p3,
    const float* __restrict__ b2a, const float4* __restrict__ pw,
    const float* __restrict__ dinv, float* __restrict__ xw2)
{
    __shared__ float h2s[4][392];   // per-wave [node2][ci16][t pad12] stride 196
    __shared__ float h3f[4][1040];  // per-wave [node2][co64][t8], node stride 520

    const int tid  = threadIdx.x;
    const int wid  = tid >> 6;
    const int lane = tid & 63;
    const int l32  = lane & 31;
    const int nl   = lane >> 5;
    const int base = blockIdx.x * 8 + wid * 2;
    const int node = base + nl;

    float* h2w = h2s[wid];
    float* h3w = h3f[wid];

    // ---- stage h2 (2 nodes x 160), transposed to [ci][t] ----
#pragma unroll
    for (int it = 0; it < 2; ++it) {
        int i = lane + it * 64;
        if (i < 80) {
            int ns = i / 40, r4 = i - ns * 40;
            int t = r4 >> 2, ci0 = (r4 & 3) << 2;
            float4 v = *(const float4*)&h2g[(size_t)(base + ns) * 160 + t * 16 + ci0];
            float* hp = &h2w[ns * 196 + ci0 * 12 + t];
            hp[0]  = v.x;
            hp[12] = v.y;
            hp[24] = v.z;
            hp[36] = v.w;
        }
    }

    // ---- conv2: (16,10) -> (64+64, 8) ----
    float acc[4][8];
    {
        float b0 = b1b[l32], b1 = b1b[l32 + 32], b2 = b1b[64 + l32], b3 = b1b[96 + l32];
#pragma unroll
        for (int t = 0; t < 8; ++t) { acc[0][t] = b0; acc[1][t] = b1; acc[2][t] = b2; acc[3][t] = b3; }
    }

#pragma unroll 1
    for (int c4 = 0; c4 < 4; ++c4) {
        float hv[4][12];
#pragma unroll
        for (int i = 0; i < 4; ++i) {
            const float* hp = &h2w[nl * 196 + (c4 * 4 + i) * 12];
            float4 v0 = *(const float4*)(hp);
            float4 v1 = *(const float4*)(hp + 4);
            float4 v2 = *(const float4*)(hp + 8);
            hv[i][0] = v0.x; hv[i][1] = v0.y; hv[i][2]  = v0.z; hv[i][3]  = v0.w;
            hv[i][4] = v1.x; hv[i][5] = v1.y; hv[i][6]  = v1.z; hv[i][7]  = v1.w;
            hv[i][8] = v2.x; hv[i][9] = v2.y; hv[i][10] = v2.z; hv[i][11] = v2.w;
        }
#pragma unroll
        for (int j = 0; j < 4; ++j) {
            float4 w0 = p2[((c4 * 4 + j) * 3 + 0) * 32 + l32];
            float4 w1 = p2[((c4 * 4 + j) * 3 + 1) * 32 + l32];
            float4 w2 = p2[((c4 * 4 + j) * 3 + 2) * 32 + l32];
            float wr[12];
            wr[0] = w0.x; wr[1] = w0.y; wr[2]  = w0.z; wr[3]  = w0.w;
            wr[4] = w1.x; wr[5] = w1.y; wr[6]  = w1.z; wr[7]  = w1.w;
            wr[8] = w2.x; wr[9] = w2.y; wr[10] = w2.z; wr[11] = w2.w;
#pragma unroll
            for (int i = 0; i < 4; ++i)
#pragma unroll
                for (int k = 0; k < 3; ++k)
#pragma unroll
                    for (int t = 0; t < 8; ++t)
                        acc[j][t] = fmaf(wr[i * 3 + k], hv[i][t + k], acc[j][t]);
        }
    }

    // GLU -> h3 (2 co rows per lane), write ONCE into full h3 buffer
    {
        float r0[8], r1[8];
#pragma unroll
        for (int t = 0; t < 8; ++t) {
            r0[t] = acc[0][t] * sigf(acc[2][t]);   // co = l32
            r1[t] = acc[1][t] * sigf(acc[3][t]);   // co = l32+32
        }
        float* hp0 = &h3w[nl * 520 + l32 * 8];
        *(float4*)(hp0)     = make_float4(r0[0], r0[1], r0[2], r0[3]);
        *(float4*)(hp0 + 4) = make_float4(r0[4], r0[5], r0[6], r0[7]);
        float* hp1 = &h3w[nl * 520 + (l32 + 32) * 8];
        *(float4*)(hp1)     = make_float4(r1[0], r1[1], r1[2], r1[3]);
        *(float4*)(hp1 + 4) = make_float4(r1[4], r1[5], r1[6], r1[7]);
    }

    // ---- conv3: (64,8) -> (64+64, 6), single flat pass ----
    float c3[4][6];
    {
        float b0 = b2a[l32], b1 = b2a[l32 + 32], b2 = b2a[64 + l32], b3 = b2a[96 + l32];
#pragma unroll
        for (int t = 0; t < 6; ++t) { c3[0][t] = b0; c3[1][t] = b1; c3[2][t] = b2; c3[3][t] = b3; }
    }

#pragma unroll 1
    for (int c16 = 0; c16 < 16; ++c16) {
        float hv[4][8];
#pragma unroll
        for (int i = 0; i < 4; ++i) {
            const float* hp = &h3w[nl * 520 + (c16 * 4 + i) * 8];
            float4 v0 = *(const float4*)(hp);
            float4 v1 = *(const float4*)(hp + 4);
            hv[i][0] = v0.x; hv[i][1] = v0.y; hv[i][2] = v0.z; hv[i][3] = v0.w;
            hv[i][4] = v1.x; hv[i][5] = v1.y; hv[i][6] = v1.z; hv[i][7] = v1.w;
        }
#pragma unroll
        for (int j = 0; j < 4; ++j) {
            float4 w0 = p3[((c16 * 4 + j) * 3 + 0) * 32 + l32];
            float4 w1 = p3[((c16 * 4 + j) * 3 + 1) * 32 + l32];
            float4 w2 = p3[((c16 * 4 + j) * 3 + 2) * 32 + l32];
            float wr[12];
            wr[0] = w0.x; wr[1] = w0.y; wr[2]  = w0.z; wr[3]  = w0.w;
            wr[4] = w1.x; wr[5] = w1.y; wr[6]  = w1.z; wr[7]  = w1.w;
            wr[8] = w2.x; wr[9] = w2.y; wr[10] = w2.z; wr[11] = w2.w;
#pragma unroll
            for (int i = 0; i < 4; ++i)
#pragma unroll
                for (int k = 0; k < 3; ++k)
#pragma unroll
                    for (int t = 0; t < 6; ++t)
                        c3[j][t] = fmaf(wr[i * 3 + k], hv[i][t + k], c3[j][t]);
        }
    }

    // ---- GLU -> h4, overwrite h3 rows, then single-pass proj 64->16 ----
    {
        float r0[6], r1[6];
#pragma unroll
        for (int t = 0; t < 6; ++t) {
            r0[t] = c3[0][t] * sigf(c3[2][t]);   // co = l32
            r1[t] = c3[1][t] * sigf(c3[3][t]);   // co = l32+32
        }
        float* hp0 = &h3w[nl * 520 + l32 * 8];
        *(float4*)(hp0)     = make_float4(r0[0], r0[1], r0[2], r0[3]);
        *(float2*)(hp0 + 4) = make_float2(r0[4], r0[5]);
        float* hp1 = &h3w[nl * 520 + (l32 + 32) * 8];
        *(float4*)(hp1)     = make_float4(r1[0], r1[1], r1[2], r1[3]);
        *(float2*)(hp1 + 4) = make_float2(r1[4], r1[5]);
    }

    float pacc[3] = {0.f, 0.f, 0.f};
    const int d  = l32 & 15;
    const int th = l32 >> 4;   // 0: t=0..2, 1: t=3..5

#pragma unroll 1
    for (int cl4 = 0; cl4 < 16; ++cl4) {
        float4 wv = pw[cl4 * 16 + d];
        float wq[4] = {wv.x, wv.y, wv.z, wv.w};
#pragma unroll
        for (int c = 0; c < 4; ++c) {
            const float* hp = &h3w[nl * 520 + (cl4 * 4 + c) * 8];
            float4 e0 = *(const float4*)(hp);
            float2 e1 = *(const float2*)(hp + 4);
            float s0 = th ? e0.w : e0.x;
            float s1 = th ? e1.x : e0.y;
            float s2 = th ? e1.y : e0.z;
            pacc[0] = fmaf(wq[c], s0, pacc[0]);
            pacc[1] = fmaf(wq[c], s1, pacc[1]);
            pacc[2] = fmaf(wq[c], s2, pacc[2]);
        }
    }

    const float dv = dinv[node];
#pragma unroll
    for (int s = 0; s < 3; ++s)
        xw2[(size_t)node * 96 + (th * 3 + s) * 16 + d] = pacc[s] * dv;
}

// ---- counts per graph -----------------------------------------------------
__global__ void k_counts(const int* __restrict__ batch, float* __restrict__ cnt,
                         int n, int ngraphs)
{
    int g = threadIdx.x;
    if (g >= ngraphs) return;
    int lo = 0, hi = n;
    while (lo < hi) { int m = (lo + hi) >> 1; if (batch[m] < g) lo = m + 1; else hi = m; }
    int lo2 = 0, hi2 = n;
    while (lo2 < hi2) { int m = (lo2 + hi2) >> 1; if (batch[m] < g + 1) lo2 = m + 1; else hi2 = m; }
    cnt[g] = (float)(lo2 - lo);
}

// ---- mean-pool numerator --------------------------------------------------
__global__ __launch_bounds__(128) void k_pool(
    const float* __restrict__ h5, const int* __restrict__ batch,
    float* __restrict__ pool, int nNodes)
{
    int j = threadIdx.x;
    if (j >= 96) return;
    int n0 = blockIdx.x * 64;
    int n1 = min(n0 + 64, nNodes);
    int cur = batch[n0];
    float acc = 0.f;
    for (int n = n0; n < n1; ++n) {
        int g = batch[n];
        if (g != cur) { atomicAdd(&pool[cur * 96 + j], acc); acc = 0.f; cur = g; }
        acc += h5[(size_t)n * 96 + j];
    }
    atomicAdd(&pool[cur * 96 + j], acc);
}

// ---- final conv_glu -------------------------------------------------------
__global__ __launch_bounds__(256) void k_final(
    const float* __restrict__ pool, const float* __restrict__ cnt,
    const float* __restrict__ w, const float* __restrict__ b,
    float* __restrict__ out)
{
    __shared__ float m[96];
    __shared__ float ws[6144];
    __shared__ float bs[128];
    int g = blockIdx.x, tid = threadIdx.x;
    if (tid < 96) m[tid] = pool[g * 96 + tid] / fmaxf(cnt[g], 1.0f);
    for (int i = tid; i < 6144; i += 256) ws[i] = w[i];
    if (tid < 128) bs[tid] = b[tid];
    __syncthreads();

    int c = tid >> 2, t = tid & 3;
    float a = bs[c], gg = bs[c + 64];
#pragma unroll
    for (int ci = 0; ci < 16; ++ci)
#pragma unroll
        for (int k = 0; k < 3; ++k) {
            float xv = m[(t + k) * 16 + ci];
            a  = fmaf(ws[c * 48 + ci * 3 + k],        xv, a);
            gg = fmaf(ws[(c + 64) * 48 + ci * 3 + k], xv, gg);
        }
    out[g * 256 + c * 4 + t] = a * sigf(gg);
}

// ---------------------------------------------------------------------------
extern "C" void kernel_launch(void* const* d_in, const int* in_sizes, int n_in,
                              void* d_out, int out_size, void* d_ws, size_t ws_size,
                              hipStream_t stream)
{
    const float* x      = (const float*)d_in[0];
    const int*   ei     = (const int*)  d_in[1];
    const int*   batch  = (const int*)  d_in[2];
    const float* w_t1a  = (const float*)d_in[3];
    const float* b_t1a  = (const float*)d_in[4];
    const float* w_s1   = (const float*)d_in[5];
    const float* bb_s1  = (const float*)d_in[6];
    const float* w_t1b  = (const float*)d_in[7];
    const float* b_t1b  = (const float*)d_in[8];
    const float* w_t2a  = (const float*)d_in[9];
    const float* b_t2a  = (const float*)d_in[10];
    const float* w_s2   = (const float*)d_in[11];
    const float* bb_s2  = (const float*)d_in[12];
    const float* w_t2b  = (const float*)d_in[13];
    const float* b_t2b  = (const float*)d_in[14];
    float* out = (float*)d_out;

    const int* row = ei;
    const int* col = ei + NE;

    // workspace layout
    float* F    = (float*)d_ws;
    float* xw   = F;                         // NN*160
    float* h    = xw + (size_t)NN * 160;     // NN*160
    float* p2f  = h  + (size_t)NN * 160;     // 6144
    float* p3f  = p2f + 6144;                // 24576
    float* pwf  = p3f + 24576;               // 1024
    float* dinv = pwf + 1024;                // NN
    float* pool = dinv + NN;                 // NG*96
    float* gcnt = pool + NG * 96;            // NG
    int*   cnt  = (int*)(gcnt + NG);         // NN ints
    unsigned short* bucket = (unsigned short*)(cnt + NN); // NN*CAP ushort

    hipMemsetAsync(cnt,  0, (size_t)NN * sizeof(int), stream);
    hipMemsetAsync(pool, 0, (size_t)NG * 96 * sizeof(float), stream);

    k_fill<<<(NE + 255) / 256, 256, 0, stream>>>(row, col, cnt, bucket, NE);
    k_dinv<<<(NN + 255) / 256, 256, 0, stream>>>(cnt, dinv, NN);
    k_prep<<<24, 256, 0, stream>>>(w_t1b, w_t2a, w_s2,
                                   (float4*)p2f, (float4*)p3f, (float4*)pwf);

    k_conv1_proj<<<(NN * 10 + 255) / 256, 256, 0, stream>>>(
        x, w_t1a, b_t1a, w_s1, dinv, xw, NN);

    k_gather<160><<<(NN * 64) / 256, 256, 0, stream>>>(
        xw, bucket, cnt, dinv, bb_s1, h, NN);

    k_conv23_v7<<<NN / 8, 256, 0, stream>>>(
        h, (const float4*)p2f, b_t1b, (const float4*)p3f, b_t2a,
        (const float4*)pwf, dinv, xw);

    k_gather<96><<<(NN * 64) / 256, 256, 0, stream>>>(
        xw, bucket, cnt, dinv, bb_s2, h, NN);

    k_counts<<<1, 64, 0, stream>>>(batch, gcnt, NN, NG);
    k_pool<<<(NN + 63) / 64, 128, 0, stream>>>(h, batch, pool, NN);

    k_final<<<NG, 256, 0, stream>>>(pool, gcnt, w_t2b, b_t2b, out);
}